// Round 16
// baseline (277.186 us; speedup 1.0000x reference)
//
#include <hip/hip_runtime.h>

typedef unsigned short u16;
typedef __attribute__((ext_vector_type(8))) short bf16x8;
typedef __attribute__((ext_vector_type(16))) float f32x16;
typedef __attribute__((address_space(3))) void lds_void;
typedef __attribute__((address_space(1))) const void gbl_void;

#define NN 4
#define HH 256
#define WW 256
#define PD 258
#define CIN 64
#define EPSV 1e-5f

__device__ __forceinline__ float b2f(u16 x){ union{unsigned u; float f;} q; q.u = ((unsigned)x)<<16; return q.f; }
__device__ __forceinline__ u16 f2b(float f){ union{float f; unsigned u;} q; q.f = f; unsigned r = q.u + 0x7FFF + ((q.u>>16)&1u); return (u16)(r>>16); }
__device__ __forceinline__ float leakyf(float x){ return x >= 0.f ? x : 0.01f*x; }

template<int N> __device__ __forceinline__ void waitvm(){
  asm volatile("s_waitcnt vmcnt(%0) lgkmcnt(0)" :: "n"(N) : "memory");
  __builtin_amdgcn_sched_barrier(0);
}
__device__ __forceinline__ void waitlg(){
  asm volatile("s_waitcnt lgkmcnt(0)" ::: "memory");
  __builtin_amdgcn_sched_barrier(0);
}

// ---------- prep: weights OIHW f32 -> [kq][cg][tap][lane][8] bf16 (32x32x16 fragment-major) ----------
__global__ void prep_kernel(const float* __restrict__ w1, const float* __restrict__ wf,
                            const float* __restrict__ w2, const float* __restrict__ wr,
                            u16* __restrict__ wB1, u16* __restrict__ wBf,
                            u16* __restrict__ wB2, u16* __restrict__ wBr){
  int idx = blockIdx.x*256 + threadIdx.x;
  if (idx < 36864){                       // 4kq * 2cg * 9tap * 64lane * 8
    int e = idx & 7, lane = (idx >> 3) & 63, rest = idx >> 9;
    int tap = rest % 9, rest2 = rest / 9;
    int cg = rest2 & 1, kq = rest2 >> 1;
    int cout = cg*32 + (lane & 31);
    int cin  = kq*16 + (lane >> 5)*8 + e;
    int src = (cout*64 + cin)*9 + tap;
    wB1[idx] = f2b(w1[src]);
    wB2[idx] = f2b(w2[src]);
  }
  if (idx < 55296){                       // 4kq * 3cg * 9tap * 64lane * 8
    int e = idx & 7, lane = (idx >> 3) & 63, rest = idx >> 9;
    int tap = rest % 9, rest2 = rest / 9;
    int cg = rest2 % 3, kq = rest2 / 3;
    int cout = cg*32 + (lane & 31);
    int cin  = kq*16 + (lane >> 5)*8 + e;
    float v = (cout < 72) ? wf[(cout*64 + cin)*9 + tap] : 0.f;
    wBf[idx] = f2b(v);
  }
  if (idx < 4096){                        // 1x1: 4kq * 2cg * 64lane * 8
    int e = idx & 7, lane = (idx >> 3) & 63, rest = idx >> 9;
    int cg = rest & 1, kq = rest >> 1;
    int cout = cg*32 + (lane & 31);
    int cin  = kq*16 + (lane >> 5)*8 + e;
    wBr[idx] = f2b(wr[cout*64 + cin]);
  }
}

// ---------- pad_x ----------
__global__ __launch_bounds__(256) void padx_kernel(const float* __restrict__ x, u16* __restrict__ xpad){
  int n = blockIdx.x >> 8, h = blockIdx.x & 255, t = threadIdx.x;
  u16* dstrow = xpad + ((size_t)(n*PD + h + 1)*PD)*CIN;
  const uint4 z = {0,0,0,0};
  #pragma unroll
  for (int c8 = 0; c8 < 8; ++c8){
    u16 buf[8];
    #pragma unroll
    for (int j = 0; j < 8; ++j)
      buf[j] = f2b(x[((size_t)(n*64 + c8*8 + j))*65536 + h*256 + t]);
    *(uint4*)(dstrow + (size_t)(t+1)*CIN + c8*8) = *(uint4*)buf;
  }
  if (t == 0)   { for (int c8 = 0; c8 < 8; ++c8) *(uint4*)(dstrow + 0*CIN   + c8*8) = z; }
  if (t == 255) { for (int c8 = 0; c8 < 8; ++c8) *(uint4*)(dstrow + 257*CIN + c8*8) = z; }
  if (h == 0 || h == 255){
    u16* brow = xpad + ((size_t)(n*PD + (h == 0 ? 0 : 257))*PD)*CIN;
    for (int p = t; p < PD; p += 256)
      for (int c8 = 0; c8 < 8; ++c8) *(uint4*)(brow + (size_t)p*CIN + c8*8) = z;
  }
}

// ---------- reflect borders of y1pad ----------
__global__ void reflect_kernel(u16* __restrict__ y1pad){
  int idx = blockIdx.x*256 + threadIdx.x;
  if (idx >= 4*1028*8) return;
  int n = idx/(1028*8), rem = idx%(1028*8), p = rem >> 3, cc = rem & 7;
  int pr, pc;
  if      (p < 258)  { pr = 0;   pc = p; }
  else if (p < 516)  { pr = 257; pc = p - 258; }
  else if (p < 772)  { pr = 1 + (p - 516); pc = 0; }
  else               { pr = 1 + (p - 772); pc = 257; }
  int sr = (pr == 0) ? 2 : ((pr == 257) ? 255 : pr);
  int sc = (pc == 0) ? 2 : ((pc == 257) ? 255 : pc);
  uint4 v = *(const uint4*)(y1pad + ((size_t)(n*PD + sr)*PD + sc)*CIN + cc*8);
  *(uint4*)(y1pad + ((size_t)(n*PD + pr)*PD + pc)*CIN + cc*8) = v;
}

// ---------- MFMA conv: 4 tiles/block, double-buffered windows, counted-vmcnt pipeline ----------
// Block owns row-pair h0..h0+1, tiles = col quarters. Window/tile: padded rows h0..h0+3, cols w0..w0+65.
// Buffers padded to 2304 chunks so every wave issues exactly RNDU global_load_lds per stage.
template<int NCG, int MODE>
__global__ __launch_bounds__(NCG*128, (NCG==3)?6:4) void conv_mfma(
    const u16* __restrict__ Ain, const u16* __restrict__ wB, const float* __restrict__ bias,
    u16* __restrict__ outB, float* __restrict__ outF,
    const u16* __restrict__ xpad, const u16* __restrict__ wBr,
    const float* __restrict__ br,
    float* __restrict__ bnsum, float* __restrict__ bnsumsq,
    const float* __restrict__ hmu, const float* __restrict__ hrs){

  constexpr int NC   = (MODE == 1) ? 72 : 64;
  constexpr int NCP  = NC + 8;
  constexpr int TPB  = NCG*128;
  constexpr int RNDU = 2304/TPB;                    // 9 (NCG=2) or 6 (NCG=3), uniform per wave
  constexpr int SST  = (MODE==0) ? 4 : ((MODE==1) ? 3 : 8);   // store instrs/wave/tile
  constexpr int BUFB = 2304*16;                     // 36,864 B per buffer
  __shared__ __align__(16) char smem[2*BUFB];
  __shared__ float bnacc[NCG*2*32*2];
  __shared__ float hmr[64];

  int t = threadIdx.x, lane = t & 63, wv = t >> 6;
  int l31 = lane & 31, l1 = lane >> 5;
  int cg = wv % NCG, ph = wv / NCG;
  int bid = blockIdx.x;
  int sb = (bid & 7)*64 + (bid >> 3);               // XCD swizzle (512 = 8*64, bijective)
  int n = sb >> 7, rowb = sb & 127;
  int h0 = rowb*2;

  if (MODE == 2 && t < 64) hmr[t] = (t < 32) ? hmu[n*32 + t] : hrs[n*32 + (t - 32)];

  auto STAGE = [&](int tile, char* dbuf){
    const u16* base = Ain + ((size_t)(n*PD + h0)*PD + (size_t)tile*64)*CIN;
    #pragma unroll
    for (int r = 0; r < RNDU; ++r){
      int c = r*TPB + t;
      int cc = (c < 2112) ? c : 0;
      int row = cc / 528, rem2 = cc - row*528;
      int px = rem2 >> 3, sub = rem2 & 7;
      int subs = sub ^ (px & 7);
      const u16* src = base + (size_t)row*PD*CIN + (size_t)(px*8 + subs)*8;
      __builtin_amdgcn_global_load_lds((gbl_void*)src,
                                       (lds_void*)(dbuf + (size_t)c*16), 16, 0, 0);
    }
  };

  STAGE(0, smem);
  STAGE(1, smem + BUFB);

  float bs = 0.f, bq = 0.f;
  int cout = cg*32 + l31;

  #pragma unroll
  for (int tile = 0; tile < 4; ++tile){
    char* buf = smem + (tile & 1)*BUFB;
    const int w0 = tile*64;

    // ---- start-of-tile wait: guarantee this tile's stage retired; keep newer ops in flight ----
    if (tile == 0)      waitvm<RNDU>();
    else if (tile < 3)  waitvm<SST + RNDU>();
    else                waitvm<SST>();
    __builtin_amdgcn_s_barrier();

    // ---- MODE 2: in-LDS HIN+leaky transform (+ring zero) ----
    if (MODE == 2){
      for (int c = t; c < 2112; c += TPB){
        int row = c / 528, rem2 = c - row*528;
        int px = rem2 >> 3, sub = rem2 & 7;
        int gpr = h0 + row, gpc = w0 + px;
        uint4* p = (uint4*)(buf + (size_t)c*16);
        if (gpr == 0 || gpr == 257 || gpc == 0 || gpc == 257){
          uint4 z = {0,0,0,0}; *p = z;
        } else {
          int cg8 = sub ^ (px & 7);
          uint4 v = *p;
          u16* e = (u16*)&v;
          if (cg8 < 4){
            #pragma unroll
            for (int j = 0; j < 8; ++j){
              float f = (b2f(e[j]) - hmr[cg8*8 + j]) * hmr[32 + cg8*8 + j];
              e[j] = f2b(leakyf(f));
            }
          } else {
            #pragma unroll
            for (int j = 0; j < 8; ++j) e[j] = f2b(leakyf(b2f(e[j])));
          }
          *p = v;
        }
      }
      waitlg();
      __builtin_amdgcn_s_barrier();
    }

    // ---- MFMA ----
    f32x16 acc[2];
    #pragma unroll
    for (int pg = 0; pg < 2; ++pg)
      #pragma unroll
      for (int i = 0; i < 16; ++i) acc[pg][i] = 0.f;

    #pragma unroll
    for (int kq = 0; kq < 4; ++kq){
      bf16x8 wfr[9];
      #pragma unroll
      for (int tap = 0; tap < 9; ++tap)
        wfr[tap] = *(const bf16x8*)(wB + ((size_t)((kq*NCG + cg)*9 + tap)*64 + lane)*8);
      #pragma unroll
      for (int pg = 0; pg < 2; ++pg){
        #pragma unroll
        for (int tap = 0; tap < 9; ++tap){
          int wrow = ph + tap/3;
          int wcol = pg*32 + l31 + tap%3;
          int chunk = (kq*2 + l1) ^ (wcol & 7);
          bf16x8 afr = *(const bf16x8*)(buf + ((((wrow*66 + wcol) << 3) + chunk) << 4));
          acc[pg] = __builtin_amdgcn_mfma_f32_32x32x16_bf16(afr, wfr[tap], acc[pg], 0, 0, 0);
        }
      }
    }

    if (MODE == 1){
      #pragma unroll
      for (int pg = 0; pg < 2; ++pg)
        #pragma unroll
        for (int reg = 0; reg < 16; ++reg){ float v = acc[pg][reg]; bs += v; bq += v*v; }
    }

    // ---- window reads done ----
    waitlg();
    __builtin_amdgcn_s_barrier();

    if (MODE < 2){
      u16* Bx = (u16*)buf;
      #pragma unroll
      for (int pg = 0; pg < 2; ++pg){
        float bv = (MODE == 0) ? bias[cout] : 0.f;
        #pragma unroll
        for (int reg = 0; reg < 16; ++reg){
          int rowD = (reg & 3) + 8*(reg >> 2) + 4*l1;
          int p = ph*64 + pg*32 + rowD;
          if (MODE == 0 || cout < 72)
            Bx[p*NCP + cout] = f2b(acc[pg][reg] + bv);
        }
      }
      waitlg();
      __builtin_amdgcn_s_barrier();
      constexpr int nch = NC/8;
      for (int idx = t; idx < 128*nch; idx += TPB){
        int px = idx/nch, c8 = idx - px*nch;
        int rr = px >> 6, cc = px & 63;
        uint4 v = *(const uint4*)(Bx + px*NCP + c8*8);
        if (MODE == 0)
          *(uint4*)(outB + ((size_t)(n*PD + h0 + 1 + rr)*PD + (w0 + 1 + cc))*CIN + c8*8) = v;
        else
          *(uint4*)(outB + ((size_t)(n*65536 + (h0 + rr)*256 + w0 + cc))*72 + c8*8) = v;
      }
      // copyout reads done -> safe to restage this buffer
      waitlg();
      __builtin_amdgcn_s_barrier();
      if (tile < 2) STAGE(tile + 2, buf);
    } else {
      // window dead for all waves -> restage early, epilogue overlaps the new loads
      if (tile < 2) STAGE(tile + 2, buf);
      f32x16 racc[2];
      #pragma unroll
      for (int pg = 0; pg < 2; ++pg)
        #pragma unroll
        for (int i = 0; i < 16; ++i) racc[pg][i] = 0.f;
      const u16* Xrow = xpad + ((size_t)(n*PD + h0 + 1 + ph)*PD + (w0 + 1))*CIN;
      #pragma unroll
      for (int kq = 0; kq < 4; ++kq){
        bf16x8 wr8 = *(const bf16x8*)(wBr + ((size_t)((kq*2 + cg)*64 + lane))*8);
        #pragma unroll
        for (int pg = 0; pg < 2; ++pg){
          bf16x8 xfr = *(const bf16x8*)(Xrow + (size_t)(pg*32 + l31)*CIN + kq*16 + l1*8);
          racc[pg] = __builtin_amdgcn_mfma_f32_32x32x16_bf16(xfr, wr8, racc[pg], 0, 0, 0);
        }
      }
      float bv = bias[cout], bb = br[cout];
      float* orow = outF + ((size_t)(n*64 + cout))*65536 + (h0 + ph)*256 + w0;
      #pragma unroll
      for (int pg = 0; pg < 2; ++pg){
        #pragma unroll
        for (int q = 0; q < 4; ++q){
          float4 o;
          o.x = leakyf(acc[pg][q*4+0] + bv) + racc[pg][q*4+0] + bb;
          o.y = leakyf(acc[pg][q*4+1] + bv) + racc[pg][q*4+1] + bb;
          o.z = leakyf(acc[pg][q*4+2] + bv) + racc[pg][q*4+2] + bb;
          o.w = leakyf(acc[pg][q*4+3] + bv) + racc[pg][q*4+3] + bb;
          int px = pg*32 + 8*q + 4*l1;
          *(float4*)(orow + px) = o;
        }
      }
    }
  }

  if (MODE == 1){
    bs += __shfl_xor(bs, 32); bq += __shfl_xor(bq, 32);
    if (l1 == 0){ bnacc[(wv*32 + l31)*2 + 0] = bs; bnacc[(wv*32 + l31)*2 + 1] = bq; }
    __syncthreads();
    if (t < 144){
      int c = t >> 1, which = t & 1;
      int cgf = c >> 5, ci = c & 31;
      float v = bnacc[(cgf*32 + ci)*2 + which] + bnacc[((NCG + cgf)*32 + ci)*2 + which];
      atomicAdd(which ? &bnsumsq[c] : &bnsum[c], v);
    }
  }
}

__global__ void bnfinal_kernel(const float* __restrict__ bnsum, const float* __restrict__ bnsumsq,
                               const float* __restrict__ gamma, const float* __restrict__ beta,
                               float* __restrict__ bnscale, float* __restrict__ bnshift){
  int c = threadIdx.x;
  if (c < 72){
    const float M = 262144.f;
    float mu  = bnsum[c] / M;
    float var = bnsumsq[c] / M - mu*mu;
    float sc  = gamma[c] * rsqrtf(var + EPSV);
    bnscale[c] = sc;
    bnshift[c] = beta[c] - mu*sc;
  }
}

// ---------- filter: 2x64 tile, staged window, 2 threads/pixel ----------
__global__ __launch_bounds__(256, 4) void filter_kernel(const u16* __restrict__ sig,
                                                        const u16* __restrict__ y1pad,
                                                        const float* __restrict__ bnscale,
                                                        const float* __restrict__ bnshift,
                                                        u16* __restrict__ y2pad,
                                                        float* __restrict__ hinsum,
                                                        float* __restrict__ hinsumsq){
  __shared__ __align__(16) char smem[2112*16];
  __shared__ float sc[72], sh[72];

  int t = threadIdx.x, lane = t & 63, wv = t >> 6;
  if (t < 72){ sc[t] = bnscale[t]; sh[t] = bnshift[t]; }
  int bid = blockIdx.x;
  int sb = (bid & 7)*256 + (bid >> 3);
  int n = sb >> 9, rem = sb & 511, rowb = rem >> 2, colb = rem & 3;
  int h0 = rowb*2, w0 = colb*64;
  int p = t & 127, r = p >> 6, c = p & 63, half = t >> 7;

  {
    const u16* base = y1pad + ((size_t)(n*PD + h0)*PD + w0)*CIN;
    #pragma unroll
    for (int rnd = 0; rnd < 9; ++rnd){
      if (rnd < 8 || wv == 0){
        int cch = rnd*256 + wv*64 + lane;
        int row = cch / 528, rem2 = cch - row*528;
        int px = rem2 >> 3, sub = rem2 & 7;
        int subs = sub ^ (px & 7);
        const u16* src = base + (size_t)row*PD*CIN + (size_t)(px*8 + subs)*8;
        __builtin_amdgcn_global_load_lds((gbl_void*)src,
                                         (lds_void*)(smem + (rnd*256 + wv*64)*16), 16, 0, 0);
      }
    }
  }

  float sv[72];
  const u16* sp = sig + ((size_t)(n*65536 + (h0 + r)*256 + w0 + c))*72;
  #pragma unroll
  for (int i = 0; i < 9; ++i){
    uint4 v = *(const uint4*)(sp + i*8);
    const u16* e = (const u16*)&v;
    #pragma unroll
    for (int j = 0; j < 8; ++j) sv[i*8+j] = b2f(e[j]);
  }
  __syncthreads();
  float mx = -1e30f;
  #pragma unroll
  for (int cc = 0; cc < 72; ++cc){ sv[cc] = sv[cc]*sc[cc] + sh[cc]; mx = fmaxf(mx, sv[cc]); }
  float sum = 0.f;
  #pragma unroll
  for (int cc = 0; cc < 72; ++cc){ sv[cc] = __expf(sv[cc] - mx); sum += sv[cc]; }
  float inv = -1.f/sum;
  float kv[36];
  if (half == 0){
    #pragma unroll
    for (int j = 0; j < 36; ++j) kv[j] = sv[j]*inv;
  } else {
    #pragma unroll
    for (int j = 0; j < 36; ++j) kv[j] = sv[36 + j]*inv;
  }
  #pragma unroll
  for (int c8 = 0; c8 < 4; ++c8) kv[c8*9 + 4] += 1.f;

  float o[32];
  #pragma unroll
  for (int cc = 0; cc < 32; ++cc) o[cc] = 0.f;
  #pragma unroll
  for (int i = 0; i < 3; ++i){
    #pragma unroll
    for (int j = 0; j < 3; ++j){
      int wcol = c + j, wrow = r + i;
      #pragma unroll
      for (int c8 = 0; c8 < 4; ++c8){
        int chunk = half*4 + c8;
        uint4 v = *(const uint4*)(smem + ((((wrow*66 + wcol) << 3) + (chunk ^ (wcol & 7))) << 4));
        const u16* e = (const u16*)&v;
        float k = kv[c8*9 + i*3 + j];
        #pragma unroll
        for (int jj = 0; jj < 8; ++jj) o[c8*8 + jj] = fmaf(k, b2f(e[jj]), o[c8*8 + jj]);
      }
    }
  }
  __syncthreads();

  u16* obuf = (u16*)smem;
  float* ps = (float*)(smem + 20480);
  #pragma unroll
  for (int c8 = 0; c8 < 4; ++c8){
    u16 ob[8];
    #pragma unroll
    for (int jj = 0; jj < 8; ++jj) ob[jj] = f2b(o[c8*8 + jj]);
    *(uint4*)(obuf + p*66 + (half*4 + c8)*8) = *(uint4*)ob;
  }
  __syncthreads();

  {
    int cch = t & 31, seg = t >> 5;
    float s = 0.f, q = 0.f;
    #pragma unroll
    for (int rr = 0; rr < 16; ++rr){
      float v = b2f(obuf[(seg*16 + rr)*66 + cch]);
      s += v; q += v*v;
    }
    ps[(seg*32 + cch)*2 + 0] = s; ps[(seg*32 + cch)*2 + 1] = q;
  }
  for (int idx = t; idx < 1024; idx += 256){
    int pp = idx >> 3, j = idx & 7;
    int rr = pp >> 6, cc = pp & 63;
    uint4 v = *(const uint4*)(obuf + pp*66 + j*8);
    *(uint4*)(y2pad + ((size_t)(n*PD + h0 + 1 + rr)*PD + (w0 + 1 + cc))*CIN + j*8) = v;
  }
  __syncthreads();
  if (t < 64){
    int cc = t >> 1, which = t & 1;
    float v = 0.f;
    #pragma unroll
    for (int seg = 0; seg < 8; ++seg) v += ps[(seg*32 + cc)*2 + which];
    atomicAdd(which ? &hinsumsq[n*32 + cc] : &hinsum[n*32 + cc], v);
  }
}

__global__ void hinfinal_kernel(const float* __restrict__ hinsum, const float* __restrict__ hinsumsq,
                                float* __restrict__ hmu, float* __restrict__ hrs){
  int i = threadIdx.x;
  if (i < 128){
    const float M = 65536.f;
    float mu  = hinsum[i] / M;
    float var = hinsumsq[i] / M - mu*mu;
    hmu[i] = mu;
    hrs[i] = rsqrtf(var + EPSV);
  }
}

// ---------- launch ----------
extern "C" void kernel_launch(void* const* d_in, const int* in_sizes, int n_in,
                              void* d_out, int out_size, void* d_ws, size_t ws_size,
                              hipStream_t stream){
  const float* x     = (const float*)d_in[0];
  const float* w1    = (const float*)d_in[1];
  const float* b1    = (const float*)d_in[2];
  const float* wf    = (const float*)d_in[3];
  const float* gamma = (const float*)d_in[4];
  const float* beta  = (const float*)d_in[5];
  const float* w2    = (const float*)d_in[6];
  const float* b2    = (const float*)d_in[7];
  const float* wr    = (const float*)d_in[8];
  const float* br    = (const float*)d_in[9];

  char* ws = (char*)d_ws;
  const size_t PADB = (size_t)NN*PD*PD*CIN*2;   // 34,080,768 bytes
  u16* xpad  = (u16*)(ws);
  u16* y1pad = (u16*)(ws + PADB);
  u16* y2pad = (u16*)(ws + 2*PADB);
  float* stats = (float*)(ws + 3*PADB);
  float* bnsum   = stats;        float* bnsumsq = stats + 80;
  float* bnscale = stats + 160;  float* bnshift = stats + 240;
  float* hinsum  = stats + 320;  float* hinsumsq= stats + 448;
  float* hmu     = stats + 576;  float* hrs     = stats + 704;
  u16* wB1 = (u16*)(ws + 3*PADB + 4096);
  u16* wBf = wB1 + 36864;
  u16* wB2 = wBf + 55296;
  u16* wBr = wB2 + 36864;

  u16* sig = (u16*)d_out;        // bf16 [n][hw][72], overwritten by conv2's f32 output later
  float* out = (float*)d_out;

  hipMemsetAsync(stats, 0, 4096, stream);
  prep_kernel<<<256, 256, 0, stream>>>(w1, wf, w2, wr, wB1, wBf, wB2, wBr);
  padx_kernel<<<NN*HH, 256, 0, stream>>>(x, xpad);
  conv_mfma<2,0><<<512, 256, 0, stream>>>(xpad, wB1, b1, y1pad, nullptr, nullptr, nullptr, nullptr, nullptr, nullptr, nullptr, nullptr);
  reflect_kernel<<<(4*1028*8 + 255)/256, 256, 0, stream>>>(y1pad);
  conv_mfma<3,1><<<512, 384, 0, stream>>>(y1pad, wBf, nullptr, sig, nullptr, nullptr, nullptr, nullptr, bnsum, bnsumsq, nullptr, nullptr);
  bnfinal_kernel<<<1, 80, 0, stream>>>(bnsum, bnsumsq, gamma, beta, bnscale, bnshift);
  filter_kernel<<<2048, 256, 0, stream>>>(sig, y1pad, bnscale, bnshift, y2pad, hinsum, hinsumsq);
  hinfinal_kernel<<<1, 128, 0, stream>>>(hinsum, hinsumsq, hmu, hrs);
  conv_mfma<2,2><<<512, 256, 0, stream>>>(y2pad, wB2, b2, nullptr, out, xpad, wBr, br, nullptr, nullptr, hmu, hrs);
}

// Round 17
// 218.483 us; speedup vs baseline: 1.2687x; 1.2687x over previous
//
#include <hip/hip_runtime.h>

typedef unsigned short u16;
typedef __attribute__((ext_vector_type(8))) short bf16x8;
typedef __attribute__((ext_vector_type(16))) float f32x16;
typedef __attribute__((address_space(3))) void lds_void;
typedef __attribute__((address_space(1))) const void gbl_void;

#define NN 4
#define HH 256
#define WW 256
#define PD 258
#define CIN 64
#define EPSV 1e-5f

__device__ __forceinline__ float b2f(u16 x){ union{unsigned u; float f;} q; q.u = ((unsigned)x)<<16; return q.f; }
__device__ __forceinline__ u16 f2b(float f){ union{float f; unsigned u;} q; q.f = f; unsigned r = q.u + 0x7FFF + ((q.u>>16)&1u); return (u16)(r>>16); }
__device__ __forceinline__ float leakyf(float x){ return x >= 0.f ? x : 0.01f*x; }

// ---------- prep: weights OIHW f32 -> [kq][cg][tap][lane][8] bf16 (32x32x16 fragment-major) ----------
__global__ void prep_kernel(const float* __restrict__ w1, const float* __restrict__ wf,
                            const float* __restrict__ w2, const float* __restrict__ wr,
                            u16* __restrict__ wB1, u16* __restrict__ wBf,
                            u16* __restrict__ wB2, u16* __restrict__ wBr){
  int idx = blockIdx.x*256 + threadIdx.x;
  if (idx < 36864){                       // 4kq * 2cg * 9tap * 64lane * 8
    int e = idx & 7, lane = (idx >> 3) & 63, rest = idx >> 9;
    int tap = rest % 9, rest2 = rest / 9;
    int cg = rest2 & 1, kq = rest2 >> 1;
    int cout = cg*32 + (lane & 31);
    int cin  = kq*16 + (lane >> 5)*8 + e;
    int src = (cout*64 + cin)*9 + tap;
    wB1[idx] = f2b(w1[src]);
    wB2[idx] = f2b(w2[src]);
  }
  if (idx < 55296){                       // 4kq * 3cg * 9tap * 64lane * 8
    int e = idx & 7, lane = (idx >> 3) & 63, rest = idx >> 9;
    int tap = rest % 9, rest2 = rest / 9;
    int cg = rest2 % 3, kq = rest2 / 3;
    int cout = cg*32 + (lane & 31);
    int cin  = kq*16 + (lane >> 5)*8 + e;
    float v = (cout < 72) ? wf[(cout*64 + cin)*9 + tap] : 0.f;
    wBf[idx] = f2b(v);
  }
  if (idx < 4096){                        // 1x1: 4kq * 2cg * 64lane * 8
    int e = idx & 7, lane = (idx >> 3) & 63, rest = idx >> 9;
    int cg = rest & 1, kq = rest >> 1;
    int cout = cg*32 + (lane & 31);
    int cin  = kq*16 + (lane >> 5)*8 + e;
    wBr[idx] = f2b(wr[cout*64 + cin]);
  }
}

// ---------- pad_x: x NCHW f32 -> xpad NHWC bf16 [n][258][258][64], zero borders ----------
__global__ __launch_bounds__(256) void padx_kernel(const float* __restrict__ x, u16* __restrict__ xpad){
  int n = blockIdx.x >> 8, h = blockIdx.x & 255, t = threadIdx.x;
  u16* dstrow = xpad + ((size_t)(n*PD + h + 1)*PD)*CIN;
  const uint4 z = {0,0,0,0};
  #pragma unroll
  for (int c8 = 0; c8 < 8; ++c8){
    u16 buf[8];
    #pragma unroll
    for (int j = 0; j < 8; ++j)
      buf[j] = f2b(x[((size_t)(n*64 + c8*8 + j))*65536 + h*256 + t]);
    *(uint4*)(dstrow + (size_t)(t+1)*CIN + c8*8) = *(uint4*)buf;
  }
  if (t == 0)   { for (int c8 = 0; c8 < 8; ++c8) *(uint4*)(dstrow + 0*CIN   + c8*8) = z; }
  if (t == 255) { for (int c8 = 0; c8 < 8; ++c8) *(uint4*)(dstrow + 257*CIN + c8*8) = z; }
  if (h == 0 || h == 255){
    u16* brow = xpad + ((size_t)(n*PD + (h == 0 ? 0 : 257))*PD)*CIN;
    for (int p = t; p < PD; p += 256)
      for (int c8 = 0; c8 < 8; ++c8) *(uint4*)(brow + (size_t)p*CIN + c8*8) = z;
  }
}

// ---------- reflect borders of y1pad ----------
__global__ void reflect_kernel(u16* __restrict__ y1pad){
  int idx = blockIdx.x*256 + threadIdx.x;
  if (idx >= 4*1028*8) return;
  int n = idx/(1028*8), rem = idx%(1028*8), p = rem >> 3, cc = rem & 7;
  int pr, pc;
  if      (p < 258)  { pr = 0;   pc = p; }
  else if (p < 516)  { pr = 257; pc = p - 258; }
  else if (p < 772)  { pr = 1 + (p - 516); pc = 0; }
  else               { pr = 1 + (p - 772); pc = 257; }
  int sr = (pr == 0) ? 2 : ((pr == 257) ? 255 : pr);
  int sc = (pc == 0) ? 2 : ((pc == 257) ? 255 : pc);
  uint4 v = *(const uint4*)(y1pad + ((size_t)(n*PD + sr)*PD + sc)*CIN + cc*8);
  *(uint4*)(y1pad + ((size_t)(n*PD + pr)*PD + pc)*CIN + cc*8) = v;
}

// ---------- MFMA conv core: 32x32x16, wave owns (px-half, cout-group), batched weight prefetch ----------
// MODE 0: conv1.  MODE 1: convF -> sig [n][hw][72] + BN stats.  MODE 2: conv2 with in-LDS
// HIN+leaky transform of the staged y2pad window + 1x1 residual.
template<int NCG, int MODE>
__global__ __launch_bounds__(NCG*128, 4) void conv_mfma(
    const u16* __restrict__ Ain, const u16* __restrict__ wB, const float* __restrict__ bias,
    u16* __restrict__ outB, float* __restrict__ outF,
    const u16* __restrict__ xpad, const u16* __restrict__ wBr,
    const float* __restrict__ br,
    float* __restrict__ bnsum, float* __restrict__ bnsumsq,
    const float* __restrict__ hmu, const float* __restrict__ hrs){

  constexpr int NC  = (MODE == 1) ? 72 : 64;
  constexpr int NCP = NC + 8;
  constexpr int TPB = NCG*128;
  constexpr int RND = (2112 + TPB - 1)/TPB;
  __shared__ __align__(16) char smem[2112*16];    // 33,792 B window, then Bx/bnpart
  __shared__ float hmr[64];                       // MODE 2: mu[0..31], rs[32..63]

  int t = threadIdx.x, lane = t & 63, wv = t >> 6;
  int l31 = lane & 31, l1 = lane >> 5;
  int cg = wv % NCG, ph = wv / NCG;
  int bid = blockIdx.x;
  int sb = (bid & 7)*256 + (bid >> 3);            // XCD-chunked swizzle (2048 = 8*256)
  int n = sb >> 9, rem = sb & 511, rowb = rem >> 2, colb = rem & 3;
  int h0 = rowb*2, w0 = colb*64;

  if (MODE == 2 && t < 64) hmr[t] = (t < 32) ? hmu[n*32 + t] : hrs[n*32 + (t - 32)];

  // ---- async stage window: padded rows h0..h0+3, cols w0..w0+65 (2112 x 16B) ----
  {
    const u16* base = Ain + ((size_t)(n*PD + h0)*PD + w0)*CIN;
    #pragma unroll
    for (int rnd = 0; rnd < RND; ++rnd){
      int c = rnd*TPB + t;
      if (c < 2112){
        int row = c / 528, rem2 = c - row*528;
        int px = rem2 >> 3, sub = rem2 & 7;
        int subs = sub ^ (px & 7);
        const u16* src = base + (size_t)row*PD*CIN + (size_t)(px*8 + subs)*8;
        __builtin_amdgcn_global_load_lds((gbl_void*)src,
                                         (lds_void*)(smem + (size_t)c*16), 16, 0, 0);
      }
    }
  }
  __syncthreads();

  // ---- MODE 2: in-LDS HIN+leaky transform (+ring zero) of the staged window ----
  if (MODE == 2){
    #pragma unroll
    for (int rnd = 0; rnd < RND; ++rnd){
      int c = rnd*TPB + t;
      if (c < 2112){
        int row = c / 528, rem2 = c - row*528;
        int px = rem2 >> 3, sub = rem2 & 7;
        int gpr = h0 + row, gpc = w0 + px;
        uint4* p = (uint4*)(smem + (size_t)c*16);
        if (gpr == 0 || gpr == 257 || gpc == 0 || gpc == 257){
          uint4 z = {0,0,0,0}; *p = z;
        } else {
          int cg8 = sub ^ (px & 7);         // channel chunk held at this position
          uint4 v = *p;
          u16* e = (u16*)&v;
          if (cg8 < 4){
            #pragma unroll
            for (int j = 0; j < 8; ++j){
              float f = (b2f(e[j]) - hmr[cg8*8 + j]) * hmr[32 + cg8*8 + j];
              e[j] = f2b(leakyf(f));
            }
          } else {
            #pragma unroll
            for (int j = 0; j < 8; ++j) e[j] = f2b(leakyf(b2f(e[j])));
          }
          *p = v;
        }
      }
    }
    __syncthreads();
  }

  f32x16 acc[2];
  #pragma unroll
  for (int pg = 0; pg < 2; ++pg)
    #pragma unroll
    for (int i = 0; i < 16; ++i) acc[pg][i] = 0.f;

  // ---- 4 K-quarters; per quarter: 9 tap weight frags batched to regs, then LDS A + MFMA ----
  #pragma unroll
  for (int kq = 0; kq < 4; ++kq){
    bf16x8 wfr[9];
    #pragma unroll
    for (int tap = 0; tap < 9; ++tap)
      wfr[tap] = *(const bf16x8*)(wB + ((size_t)((kq*NCG + cg)*9 + tap)*64 + lane)*8);
    #pragma unroll
    for (int pg = 0; pg < 2; ++pg){
      #pragma unroll
      for (int tap = 0; tap < 9; ++tap){
        int wrow = ph + tap/3;
        int wcol = pg*32 + l31 + tap%3;
        int chunk = (kq*2 + l1) ^ (wcol & 7);
        bf16x8 afr = *(const bf16x8*)(smem + ((((wrow*66 + wcol) << 3) + chunk) << 4));
        acc[pg] = __builtin_amdgcn_mfma_f32_32x32x16_bf16(afr, wfr[tap], acc[pg], 0, 0, 0);
      }
    }
  }

  int cout = cg*32 + l31;

  if (MODE < 2){
    __syncthreads();                          // window dead; reuse as Bx + bnpart
    u16* Bx = (u16*)smem;
    float* bnpart = (float*)(smem + 24576);   // [NW][32][2]
    if (MODE == 1){
      float s = 0.f, q = 0.f;
      #pragma unroll
      for (int pg = 0; pg < 2; ++pg)
        #pragma unroll
        for (int reg = 0; reg < 16; ++reg){ float v = acc[pg][reg]; s += v; q += v*v; }
      s += __shfl_xor(s, 32); q += __shfl_xor(q, 32);
      if (l1 == 0){ bnpart[(wv*32 + l31)*2 + 0] = s; bnpart[(wv*32 + l31)*2 + 1] = q; }
    }
    #pragma unroll
    for (int pg = 0; pg < 2; ++pg){
      float bv = (MODE == 0) ? bias[cout] : 0.f;
      #pragma unroll
      for (int reg = 0; reg < 16; ++reg){
        int rowD = (reg & 3) + 8*(reg >> 2) + 4*l1;
        int p = ph*64 + pg*32 + rowD;
        if (MODE == 0 || cout < 72)
          Bx[p*NCP + cout] = f2b(acc[pg][reg] + bv);
      }
    }
    __syncthreads();
    constexpr int nch = NC/8;
    for (int idx = t; idx < 128*nch; idx += TPB){
      int px = idx/nch, c8 = idx - px*nch;
      int rr = px >> 6, cc = px & 63;
      uint4 v = *(const uint4*)(Bx + px*NCP + c8*8);
      if (MODE == 0)
        *(uint4*)(outB + ((size_t)(n*PD + h0 + 1 + rr)*PD + (w0 + 1 + cc))*CIN + c8*8) = v;
      else
        *(uint4*)(outB + ((size_t)(n*65536 + (h0 + rr)*256 + w0 + cc))*72 + c8*8) = v;
    }
    if (MODE == 1 && t < 192){
      int c = t >> 1, which = t & 1;
      if (c < 72){
        int cgf = c >> 5, ci = c & 31;
        float v = bnpart[((cgf*32) + ci)*2 + which] + bnpart[(((NCG + cgf)*32) + ci)*2 + which];
        atomicAdd(which ? &bnsumsq[c] : &bnsum[c], v);
      }
    }
  } else {
    // 1x1 residual on xpad via MFMA, then out = leaky(conv+b2) + res + br, f32 NCHW
    f32x16 racc[2];
    #pragma unroll
    for (int pg = 0; pg < 2; ++pg)
      #pragma unroll
      for (int i = 0; i < 16; ++i) racc[pg][i] = 0.f;
    const u16* Xrow = xpad + ((size_t)(n*PD + h0 + 1 + ph)*PD + (w0 + 1))*CIN;
    #pragma unroll
    for (int kq = 0; kq < 4; ++kq){
      bf16x8 wr8 = *(const bf16x8*)(wBr + ((size_t)((kq*2 + cg)*64 + lane))*8);
      #pragma unroll
      for (int pg = 0; pg < 2; ++pg){
        bf16x8 xfr = *(const bf16x8*)(Xrow + (size_t)(pg*32 + l31)*CIN + kq*16 + l1*8);
        racc[pg] = __builtin_amdgcn_mfma_f32_32x32x16_bf16(xfr, wr8, racc[pg], 0, 0, 0);
      }
    }
    float bv = bias[cout], bb = br[cout];
    float* orow = outF + ((size_t)(n*64 + cout))*65536 + (h0 + ph)*256 + w0;
    #pragma unroll
    for (int pg = 0; pg < 2; ++pg){
      #pragma unroll
      for (int q = 0; q < 4; ++q){
        float4 o;
        o.x = leakyf(acc[pg][q*4+0] + bv) + racc[pg][q*4+0] + bb;
        o.y = leakyf(acc[pg][q*4+1] + bv) + racc[pg][q*4+1] + bb;
        o.z = leakyf(acc[pg][q*4+2] + bv) + racc[pg][q*4+2] + bb;
        o.w = leakyf(acc[pg][q*4+3] + bv) + racc[pg][q*4+3] + bb;
        int px = pg*32 + 8*q + 4*l1;
        *(float4*)(orow + px) = o;
      }
    }
  }
}

__global__ void bnfinal_kernel(const float* __restrict__ bnsum, const float* __restrict__ bnsumsq,
                               const float* __restrict__ gamma, const float* __restrict__ beta,
                               float* __restrict__ bnscale, float* __restrict__ bnshift){
  int c = threadIdx.x;
  if (c < 72){
    const float M = 262144.f;
    float mu  = bnsum[c] / M;
    float var = bnsumsq[c] / M - mu*mu;
    float sc  = gamma[c] * rsqrtf(var + EPSV);
    bnscale[c] = sc;
    bnshift[c] = beta[c] - mu*sc;
  }
}

// ---------- filter: 2x64 tile, staged window, 2 threads/pixel (channel halves in parallel) ----------
__global__ __launch_bounds__(256, 4) void filter_kernel(const u16* __restrict__ sig,
                                                        const u16* __restrict__ y1pad,
                                                        const float* __restrict__ bnscale,
                                                        const float* __restrict__ bnshift,
                                                        u16* __restrict__ y2pad,
                                                        float* __restrict__ hinsum,
                                                        float* __restrict__ hinsumsq){
  __shared__ __align__(16) char smem[2112*16];   // window; later aliased as obuf+ps
  __shared__ float sc[72], sh[72];

  int t = threadIdx.x, lane = t & 63, wv = t >> 6;
  if (t < 72){ sc[t] = bnscale[t]; sh[t] = bnshift[t]; }
  int bid = blockIdx.x;
  int sb = (bid & 7)*256 + (bid >> 3);           // 2048 = 8*256
  int n = sb >> 9, rem = sb & 511, rowb = rem >> 2, colb = rem & 3;
  int h0 = rowb*2, w0 = colb*64;
  int p = t & 127, r = p >> 6, c = p & 63, half = t >> 7;   // r, half wave-uniform

  // ---- async stage y1pad window (padded rows h0..h0+3, cols w0..w0+65) ----
  {
    const u16* base = y1pad + ((size_t)(n*PD + h0)*PD + w0)*CIN;
    #pragma unroll
    for (int rnd = 0; rnd < 9; ++rnd){
      if (rnd < 8 || wv == 0){
        int cch = rnd*256 + wv*64 + lane;
        int row = cch / 528, rem2 = cch - row*528;
        int px = rem2 >> 3, sub = rem2 & 7;
        int subs = sub ^ (px & 7);
        const u16* src = base + (size_t)row*PD*CIN + (size_t)(px*8 + subs)*8;
        __builtin_amdgcn_global_load_lds((gbl_void*)src,
                                         (lds_void*)(smem + (rnd*256 + wv*64)*16), 16, 0, 0);
      }
    }
  }

  // ---- sig load + BN affine + softmax(72) while staging flies ----
  float sv[72];
  const u16* sp = sig + ((size_t)(n*65536 + (h0 + r)*256 + w0 + c))*72;
  #pragma unroll
  for (int i = 0; i < 9; ++i){
    uint4 v = *(const uint4*)(sp + i*8);
    const u16* e = (const u16*)&v;
    #pragma unroll
    for (int j = 0; j < 8; ++j) sv[i*8+j] = b2f(e[j]);
  }
  __syncthreads();   // sc/sh + window ready
  float mx = -1e30f;
  #pragma unroll
  for (int cc = 0; cc < 72; ++cc){ sv[cc] = sv[cc]*sc[cc] + sh[cc]; mx = fmaxf(mx, sv[cc]); }
  float sum = 0.f;
  #pragma unroll
  for (int cc = 0; cc < 72; ++cc){ sv[cc] = __expf(sv[cc] - mx); sum += sv[cc]; }
  float inv = -1.f/sum;
  float kv[36];
  if (half == 0){
    #pragma unroll
    for (int j = 0; j < 36; ++j) kv[j] = sv[j]*inv;
  } else {
    #pragma unroll
    for (int j = 0; j < 36; ++j) kv[j] = sv[36 + j]*inv;
  }
  #pragma unroll
  for (int c8 = 0; c8 < 4; ++c8) kv[c8*9 + 4] += 1.f;   // kern = delta - softmax

  // ---- 9 taps from LDS window, o[32] accum ----
  float o[32];
  #pragma unroll
  for (int cc = 0; cc < 32; ++cc) o[cc] = 0.f;
  #pragma unroll
  for (int i = 0; i < 3; ++i){
    #pragma unroll
    for (int j = 0; j < 3; ++j){
      int wcol = c + j, wrow = r + i;
      #pragma unroll
      for (int c8 = 0; c8 < 4; ++c8){
        int chunk = half*4 + c8;
        uint4 v = *(const uint4*)(smem + ((((wrow*66 + wcol) << 3) + (chunk ^ (wcol & 7))) << 4));
        const u16* e = (const u16*)&v;
        float k = kv[c8*9 + i*3 + j];
        #pragma unroll
        for (int jj = 0; jj < 8; ++jj) o[c8*8 + jj] = fmaf(k, b2f(e[jj]), o[c8*8 + jj]);
      }
    }
  }
  __syncthreads();   // window dead; alias obuf/ps

  u16* obuf = (u16*)smem;               // 128*66 u16 = 16,896 B
  float* ps = (float*)(smem + 20480);   // [8][32][2] = 2 KB
  #pragma unroll
  for (int c8 = 0; c8 < 4; ++c8){
    u16 ob[8];
    #pragma unroll
    for (int jj = 0; jj < 8; ++jj) ob[jj] = f2b(o[c8*8 + jj]);
    *(uint4*)(obuf + p*66 + (half*4 + c8)*8) = *(uint4*)ob;
  }
  __syncthreads();

  // HIN partial stats (channels 0..31), transpose read
  {
    int cch = t & 31, seg = t >> 5;    // 8 segs x 16 px
    float s = 0.f, q = 0.f;
    #pragma unroll
    for (int rr = 0; rr < 16; ++rr){
      float v = b2f(obuf[(seg*16 + rr)*66 + cch]);
      s += v; q += v*v;
    }
    ps[(seg*32 + cch)*2 + 0] = s; ps[(seg*32 + cch)*2 + 1] = q;
  }
  // coalesced y2pad write
  for (int idx = t; idx < 1024; idx += 256){
    int pp = idx >> 3, j = idx & 7;
    int rr = pp >> 6, cc = pp & 63;
    uint4 v = *(const uint4*)(obuf + pp*66 + j*8);
    *(uint4*)(y2pad + ((size_t)(n*PD + h0 + 1 + rr)*PD + (w0 + 1 + cc))*CIN + j*8) = v;
  }
  __syncthreads();
  if (t < 64){
    int cc = t >> 1, which = t & 1;
    float v = 0.f;
    #pragma unroll
    for (int seg = 0; seg < 8; ++seg) v += ps[(seg*32 + cc)*2 + which];
    atomicAdd(which ? &hinsumsq[n*32 + cc] : &hinsum[n*32 + cc], v);
  }
}

__global__ void hinfinal_kernel(const float* __restrict__ hinsum, const float* __restrict__ hinsumsq,
                                float* __restrict__ hmu, float* __restrict__ hrs){
  int i = threadIdx.x;
  if (i < 128){
    const float M = 65536.f;
    float mu  = hinsum[i] / M;
    float var = hinsumsq[i] / M - mu*mu;
    hmu[i] = mu;
    hrs[i] = rsqrtf(var + EPSV);
  }
}

// ---------- launch ----------
extern "C" void kernel_launch(void* const* d_in, const int* in_sizes, int n_in,
                              void* d_out, int out_size, void* d_ws, size_t ws_size,
                              hipStream_t stream){
  const float* x     = (const float*)d_in[0];
  const float* w1    = (const float*)d_in[1];
  const float* b1    = (const float*)d_in[2];
  const float* wf    = (const float*)d_in[3];
  const float* gamma = (const float*)d_in[4];
  const float* beta  = (const float*)d_in[5];
  const float* w2    = (const float*)d_in[6];
  const float* b2    = (const float*)d_in[7];
  const float* wr    = (const float*)d_in[8];
  const float* br    = (const float*)d_in[9];

  char* ws = (char*)d_ws;
  const size_t PADB = (size_t)NN*PD*PD*CIN*2;   // 34,080,768 bytes
  u16* xpad  = (u16*)(ws);
  u16* y1pad = (u16*)(ws + PADB);
  u16* y2pad = (u16*)(ws + 2*PADB);
  float* stats = (float*)(ws + 3*PADB);
  float* bnsum   = stats;        float* bnsumsq = stats + 80;
  float* bnscale = stats + 160;  float* bnshift = stats + 240;
  float* hinsum  = stats + 320;  float* hinsumsq= stats + 448;
  float* hmu     = stats + 576;  float* hrs     = stats + 704;
  u16* wB1 = (u16*)(ws + 3*PADB + 4096);
  u16* wBf = wB1 + 36864;
  u16* wB2 = wBf + 55296;
  u16* wBr = wB2 + 36864;

  u16* sig = (u16*)d_out;        // 37.7MB bf16 [n][hw][72], overwritten by conv2's f32 output later
  float* out = (float*)d_out;

  hipMemsetAsync(stats, 0, 4096, stream);
  prep_kernel<<<256, 256, 0, stream>>>(w1, wf, w2, wr, wB1, wBf, wB2, wBr);
  padx_kernel<<<NN*HH, 256, 0, stream>>>(x, xpad);
  conv_mfma<2,0><<<2048, 256, 0, stream>>>(xpad, wB1, b1, y1pad, nullptr, nullptr, nullptr, nullptr, nullptr, nullptr, nullptr, nullptr);
  reflect_kernel<<<(4*1028*8 + 255)/256, 256, 0, stream>>>(y1pad);
  conv_mfma<3,1><<<2048, 384, 0, stream>>>(y1pad, wBf, nullptr, sig, nullptr, nullptr, nullptr, nullptr, bnsum, bnsumsq, nullptr, nullptr);
  bnfinal_kernel<<<1, 80, 0, stream>>>(bnsum, bnsumsq, gamma, beta, bnscale, bnshift);
  filter_kernel<<<2048, 256, 0, stream>>>(sig, y1pad, bnscale, bnshift, y2pad, hinsum, hinsumsq);
  hinfinal_kernel<<<1, 128, 0, stream>>>(hinsum, hinsumsq, hmu, hrs);
  conv_mfma<2,2><<<2048, 256, 0, stream>>>(y2pad, wB2, b2, nullptr, out, xpad, wBr, br, nullptr, nullptr, hmu, hrs);
}

// Round 18
// 216.508 us; speedup vs baseline: 1.2803x; 1.0091x over previous
//
#include <hip/hip_runtime.h>

typedef unsigned short u16;
typedef __attribute__((ext_vector_type(8))) short bf16x8;
typedef __attribute__((ext_vector_type(16))) float f32x16;
typedef __attribute__((address_space(3))) void lds_void;
typedef __attribute__((address_space(1))) const void gbl_void;

#define NN 4
#define HH 256
#define WW 256
#define PD 258
#define CIN 64
#define EPSV 1e-5f

__device__ __forceinline__ float b2f(u16 x){ union{unsigned u; float f;} q; q.u = ((unsigned)x)<<16; return q.f; }
__device__ __forceinline__ u16 f2b(float f){ union{float f; unsigned u;} q; q.f = f; unsigned r = q.u + 0x7FFF + ((q.u>>16)&1u); return (u16)(r>>16); }
__device__ __forceinline__ float leakyf(float x){ return x >= 0.f ? x : 0.01f*x; }

// ---------- prep: weights OIHW f32 -> [kq][cg][tap][lane][8] bf16 (32x32x16 fragment-major) ----------
__global__ void prep_kernel(const float* __restrict__ w1, const float* __restrict__ wf,
                            const float* __restrict__ w2, const float* __restrict__ wr,
                            u16* __restrict__ wB1, u16* __restrict__ wBf,
                            u16* __restrict__ wB2, u16* __restrict__ wBr){
  int idx = blockIdx.x*256 + threadIdx.x;
  if (idx < 36864){                       // 4kq * 2cg * 9tap * 64lane * 8
    int e = idx & 7, lane = (idx >> 3) & 63, rest = idx >> 9;
    int tap = rest % 9, rest2 = rest / 9;
    int cg = rest2 & 1, kq = rest2 >> 1;
    int cout = cg*32 + (lane & 31);
    int cin  = kq*16 + (lane >> 5)*8 + e;
    int src = (cout*64 + cin)*9 + tap;
    wB1[idx] = f2b(w1[src]);
    wB2[idx] = f2b(w2[src]);
  }
  if (idx < 55296){                       // 4kq * 3cg * 9tap * 64lane * 8
    int e = idx & 7, lane = (idx >> 3) & 63, rest = idx >> 9;
    int tap = rest % 9, rest2 = rest / 9;
    int cg = rest2 % 3, kq = rest2 / 3;
    int cout = cg*32 + (lane & 31);
    int cin  = kq*16 + (lane >> 5)*8 + e;
    float v = (cout < 72) ? wf[(cout*64 + cin)*9 + tap] : 0.f;
    wBf[idx] = f2b(v);
  }
  if (idx < 4096){                        // 1x1: 4kq * 2cg * 64lane * 8
    int e = idx & 7, lane = (idx >> 3) & 63, rest = idx >> 9;
    int cg = rest & 1, kq = rest >> 1;
    int cout = cg*32 + (lane & 31);
    int cin  = kq*16 + (lane >> 5)*8 + e;
    wBr[idx] = f2b(wr[cout*64 + cin]);
  }
}

// ---------- pad_x: x NCHW f32 -> xpad NHWC bf16 [n][258][258][64], zero borders ----------
__global__ __launch_bounds__(256) void padx_kernel(const float* __restrict__ x, u16* __restrict__ xpad){
  int n = blockIdx.x >> 8, h = blockIdx.x & 255, t = threadIdx.x;
  u16* dstrow = xpad + ((size_t)(n*PD + h + 1)*PD)*CIN;
  const uint4 z = {0,0,0,0};
  #pragma unroll
  for (int c8 = 0; c8 < 8; ++c8){
    u16 buf[8];
    #pragma unroll
    for (int j = 0; j < 8; ++j)
      buf[j] = f2b(x[((size_t)(n*64 + c8*8 + j))*65536 + h*256 + t]);
    *(uint4*)(dstrow + (size_t)(t+1)*CIN + c8*8) = *(uint4*)buf;
  }
  if (t == 0)   { for (int c8 = 0; c8 < 8; ++c8) *(uint4*)(dstrow + 0*CIN   + c8*8) = z; }
  if (t == 255) { for (int c8 = 0; c8 < 8; ++c8) *(uint4*)(dstrow + 257*CIN + c8*8) = z; }
  if (h == 0 || h == 255){
    u16* brow = xpad + ((size_t)(n*PD + (h == 0 ? 0 : 257))*PD)*CIN;
    for (int p = t; p < PD; p += 256)
      for (int c8 = 0; c8 < 8; ++c8) *(uint4*)(brow + (size_t)p*CIN + c8*8) = z;
  }
}

// ---------- reflect borders of y1pad ----------
__global__ void reflect_kernel(u16* __restrict__ y1pad){
  int idx = blockIdx.x*256 + threadIdx.x;
  if (idx >= 4*1028*8) return;
  int n = idx/(1028*8), rem = idx%(1028*8), p = rem >> 3, cc = rem & 7;
  int pr, pc;
  if      (p < 258)  { pr = 0;   pc = p; }
  else if (p < 516)  { pr = 257; pc = p - 258; }
  else if (p < 772)  { pr = 1 + (p - 516); pc = 0; }
  else               { pr = 1 + (p - 772); pc = 257; }
  int sr = (pr == 0) ? 2 : ((pr == 257) ? 255 : pr);
  int sc = (pc == 0) ? 2 : ((pc == 257) ? 255 : pc);
  uint4 v = *(const uint4*)(y1pad + ((size_t)(n*PD + sr)*PD + sc)*CIN + cc*8);
  *(uint4*)(y1pad + ((size_t)(n*PD + pr)*PD + pc)*CIN + cc*8) = v;
}

// ---------- MFMA conv core: 32x32x16, chunk-major window [row][cseg][px] (stride-1 ds_reads) ----------
// MODE 0: conv1.  MODE 1: convF -> sig [n][hw][72] + BN stats.  MODE 2: conv2 with in-LDS
// HIN+leaky transform of the staged y2pad window + 1x1 residual.
template<int NCG, int MODE>
__global__ __launch_bounds__(NCG*128, 4) void conv_mfma(
    const u16* __restrict__ Ain, const u16* __restrict__ wB, const float* __restrict__ bias,
    u16* __restrict__ outB, float* __restrict__ outF,
    const u16* __restrict__ xpad, const u16* __restrict__ wBr,
    const float* __restrict__ br,
    float* __restrict__ bnsum, float* __restrict__ bnsumsq,
    const float* __restrict__ hmu, const float* __restrict__ hrs){

  constexpr int NC  = (MODE == 1) ? 72 : 64;
  constexpr int NCP = NC + 8;
  constexpr int TPB = NCG*128;
  constexpr int RND = (2112 + TPB - 1)/TPB;
  __shared__ __align__(16) char smem[2112*16];    // 33,792 B window, then Bx/bnpart
  __shared__ float hmr[64];                       // MODE 2: mu[0..31], rs[32..63]

  int t = threadIdx.x, lane = t & 63, wv = t >> 6;
  int l31 = lane & 31, l1 = lane >> 5;
  int cg = wv % NCG, ph = wv / NCG;
  int bid = blockIdx.x;
  int sb = (bid & 7)*256 + (bid >> 3);            // XCD-chunked swizzle (2048 = 8*256)
  int n = sb >> 9, rem = sb & 511, rowb = rem >> 2, colb = rem & 3;
  int h0 = rowb*2, w0 = colb*64;

  if (MODE == 2 && t < 64) hmr[t] = (t < 32) ? hmu[n*32 + t] : hrs[n*32 + (t - 32)];

  // ---- async stage window, chunk-major: L = row*528 + cseg*66 + px ----
  {
    const u16* base = Ain + ((size_t)(n*PD + h0)*PD + w0)*CIN;
    #pragma unroll
    for (int rnd = 0; rnd < RND; ++rnd){
      int c = rnd*TPB + t;
      if (c < 2112){
        int row = c / 528, rem2 = c - row*528;
        int cseg = rem2 / 66, px = rem2 - cseg*66;
        const u16* src = base + (size_t)row*PD*CIN + (size_t)px*CIN + cseg*8;
        __builtin_amdgcn_global_load_lds((gbl_void*)src,
                                         (lds_void*)(smem + (size_t)c*16), 16, 0, 0);
      }
    }
  }
  __syncthreads();

  // ---- MODE 2: in-LDS HIN+leaky transform (+ring zero) of the staged window ----
  if (MODE == 2){
    #pragma unroll
    for (int rnd = 0; rnd < RND; ++rnd){
      int c = rnd*TPB + t;
      if (c < 2112){
        int row = c / 528, rem2 = c - row*528;
        int cseg = rem2 / 66, px = rem2 - cseg*66;
        int gpr = h0 + row, gpc = w0 + px;
        uint4* p = (uint4*)(smem + (size_t)c*16);
        if (gpr == 0 || gpr == 257 || gpc == 0 || gpc == 257){
          uint4 z = {0,0,0,0}; *p = z;
        } else {
          uint4 v = *p;
          u16* e = (u16*)&v;
          if (cseg < 4){
            #pragma unroll
            for (int j = 0; j < 8; ++j){
              float f = (b2f(e[j]) - hmr[cseg*8 + j]) * hmr[32 + cseg*8 + j];
              e[j] = f2b(leakyf(f));
            }
          } else {
            #pragma unroll
            for (int j = 0; j < 8; ++j) e[j] = f2b(leakyf(b2f(e[j])));
          }
          *p = v;
        }
      }
    }
    __syncthreads();
  }

  f32x16 acc[2];
  #pragma unroll
  for (int pg = 0; pg < 2; ++pg)
    #pragma unroll
    for (int i = 0; i < 16; ++i) acc[pg][i] = 0.f;

  // ---- 4 K-quarters; per quarter: 9 tap weight frags batched to regs, then LDS A + MFMA ----
  #pragma unroll
  for (int kq = 0; kq < 4; ++kq){
    bf16x8 wfr[9];
    #pragma unroll
    for (int tap = 0; tap < 9; ++tap)
      wfr[tap] = *(const bf16x8*)(wB + ((size_t)((kq*NCG + cg)*9 + tap)*64 + lane)*8);
    #pragma unroll
    for (int pg = 0; pg < 2; ++pg){
      #pragma unroll
      for (int tap = 0; tap < 9; ++tap){
        int wrow = ph + tap/3;
        int wcol = pg*32 + l31 + tap%3;
        int L = (wrow*8 + kq*2 + l1)*66 + wcol;
        bf16x8 afr = *(const bf16x8*)(smem + ((size_t)L << 4));
        acc[pg] = __builtin_amdgcn_mfma_f32_32x32x16_bf16(afr, wfr[tap], acc[pg], 0, 0, 0);
      }
    }
  }

  int cout = cg*32 + l31;

  if (MODE < 2){
    __syncthreads();                          // window dead; reuse as Bx + bnpart
    u16* Bx = (u16*)smem;
    float* bnpart = (float*)(smem + 24576);   // [NW][32][2]
    if (MODE == 1){
      float s = 0.f, q = 0.f;
      #pragma unroll
      for (int pg = 0; pg < 2; ++pg)
        #pragma unroll
        for (int reg = 0; reg < 16; ++reg){ float v = acc[pg][reg]; s += v; q += v*v; }
      s += __shfl_xor(s, 32); q += __shfl_xor(q, 32);
      if (l1 == 0){ bnpart[(wv*32 + l31)*2 + 0] = s; bnpart[(wv*32 + l31)*2 + 1] = q; }
    }
    #pragma unroll
    for (int pg = 0; pg < 2; ++pg){
      float bv = (MODE == 0) ? bias[cout] : 0.f;
      #pragma unroll
      for (int reg = 0; reg < 16; ++reg){
        int rowD = (reg & 3) + 8*(reg >> 2) + 4*l1;
        int p = ph*64 + pg*32 + rowD;
        if (MODE == 0 || cout < 72)
          Bx[p*NCP + cout] = f2b(acc[pg][reg] + bv);
      }
    }
    __syncthreads();
    constexpr int nch = NC/8;
    for (int idx = t; idx < 128*nch; idx += TPB){
      int px = idx/nch, c8 = idx - px*nch;
      int rr = px >> 6, cc = px & 63;
      uint4 v = *(const uint4*)(Bx + px*NCP + c8*8);
      if (MODE == 0)
        *(uint4*)(outB + ((size_t)(n*PD + h0 + 1 + rr)*PD + (w0 + 1 + cc))*CIN + c8*8) = v;
      else
        *(uint4*)(outB + ((size_t)(n*65536 + (h0 + rr)*256 + w0 + cc))*72 + c8*8) = v;
    }
    if (MODE == 1 && t < 192){
      int c = t >> 1, which = t & 1;
      if (c < 72){
        int cgf = c >> 5, ci = c & 31;
        float v = bnpart[((cgf*32) + ci)*2 + which] + bnpart[(((NCG + cgf)*32) + ci)*2 + which];
        atomicAdd(which ? &bnsumsq[c] : &bnsum[c], v);
      }
    }
  } else {
    // 1x1 residual on xpad via MFMA, then out = leaky(conv+b2) + res + br, f32 NCHW
    f32x16 racc[2];
    #pragma unroll
    for (int pg = 0; pg < 2; ++pg)
      #pragma unroll
      for (int i = 0; i < 16; ++i) racc[pg][i] = 0.f;
    const u16* Xrow = xpad + ((size_t)(n*PD + h0 + 1 + ph)*PD + (w0 + 1))*CIN;
    #pragma unroll
    for (int kq = 0; kq < 4; ++kq){
      bf16x8 wr8 = *(const bf16x8*)(wBr + ((size_t)((kq*2 + cg)*64 + lane))*8);
      #pragma unroll
      for (int pg = 0; pg < 2; ++pg){
        bf16x8 xfr = *(const bf16x8*)(Xrow + (size_t)(pg*32 + l31)*CIN + kq*16 + l1*8);
        racc[pg] = __builtin_amdgcn_mfma_f32_32x32x16_bf16(xfr, wr8, racc[pg], 0, 0, 0);
      }
    }
    float bv = bias[cout], bb = br[cout];
    float* orow = outF + ((size_t)(n*64 + cout))*65536 + (h0 + ph)*256 + w0;
    #pragma unroll
    for (int pg = 0; pg < 2; ++pg){
      #pragma unroll
      for (int q = 0; q < 4; ++q){
        float4 o;
        o.x = leakyf(acc[pg][q*4+0] + bv) + racc[pg][q*4+0] + bb;
        o.y = leakyf(acc[pg][q*4+1] + bv) + racc[pg][q*4+1] + bb;
        o.z = leakyf(acc[pg][q*4+2] + bv) + racc[pg][q*4+2] + bb;
        o.w = leakyf(acc[pg][q*4+3] + bv) + racc[pg][q*4+3] + bb;
        int px = pg*32 + 8*q + 4*l1;
        *(float4*)(orow + px) = o;
      }
    }
  }
}

__global__ void bnfinal_kernel(const float* __restrict__ bnsum, const float* __restrict__ bnsumsq,
                               const float* __restrict__ gamma, const float* __restrict__ beta,
                               float* __restrict__ bnscale, float* __restrict__ bnshift){
  int c = threadIdx.x;
  if (c < 72){
    const float M = 262144.f;
    float mu  = bnsum[c] / M;
    float var = bnsumsq[c] / M - mu*mu;
    float sc  = gamma[c] * rsqrtf(var + EPSV);
    bnscale[c] = sc;
    bnshift[c] = beta[c] - mu*sc;
  }
}

// ---------- filter: 2x64 tile, chunk-major staged window, 2 threads/pixel ----------
__global__ __launch_bounds__(256, 4) void filter_kernel(const u16* __restrict__ sig,
                                                        const u16* __restrict__ y1pad,
                                                        const float* __restrict__ bnscale,
                                                        const float* __restrict__ bnshift,
                                                        u16* __restrict__ y2pad,
                                                        float* __restrict__ hinsum,
                                                        float* __restrict__ hinsumsq){
  __shared__ __align__(16) char smem[2112*16];   // window; later aliased as obuf+ps
  __shared__ float sc[72], sh[72];

  int t = threadIdx.x, lane = t & 63, wv = t >> 6;
  if (t < 72){ sc[t] = bnscale[t]; sh[t] = bnshift[t]; }
  int bid = blockIdx.x;
  int sb = (bid & 7)*256 + (bid >> 3);           // 2048 = 8*256
  int n = sb >> 9, rem = sb & 511, rowb = rem >> 2, colb = rem & 3;
  int h0 = rowb*2, w0 = colb*64;
  int p = t & 127, r = p >> 6, c = p & 63, half = t >> 7;   // r, half wave-uniform

  // ---- async stage y1pad window, chunk-major: L = row*528 + cseg*66 + px ----
  {
    const u16* base = y1pad + ((size_t)(n*PD + h0)*PD + w0)*CIN;
    #pragma unroll
    for (int rnd = 0; rnd < 9; ++rnd){
      if (rnd < 8 || wv == 0){
        int cch = rnd*256 + wv*64 + lane;
        int row = cch / 528, rem2 = cch - row*528;
        int cseg = rem2 / 66, px = rem2 - cseg*66;
        const u16* src = base + (size_t)row*PD*CIN + (size_t)px*CIN + cseg*8;
        __builtin_amdgcn_global_load_lds((gbl_void*)src,
                                         (lds_void*)(smem + (rnd*256 + wv*64)*16), 16, 0, 0);
      }
    }
  }

  // ---- sig load + BN affine + softmax(72) while staging flies ----
  float sv[72];
  const u16* sp = sig + ((size_t)(n*65536 + (h0 + r)*256 + w0 + c))*72;
  #pragma unroll
  for (int i = 0; i < 9; ++i){
    uint4 v = *(const uint4*)(sp + i*8);
    const u16* e = (const u16*)&v;
    #pragma unroll
    for (int j = 0; j < 8; ++j) sv[i*8+j] = b2f(e[j]);
  }
  __syncthreads();   // sc/sh + window ready
  float mx = -1e30f;
  #pragma unroll
  for (int cc = 0; cc < 72; ++cc){ sv[cc] = sv[cc]*sc[cc] + sh[cc]; mx = fmaxf(mx, sv[cc]); }
  float sum = 0.f;
  #pragma unroll
  for (int cc = 0; cc < 72; ++cc){ sv[cc] = __expf(sv[cc] - mx); sum += sv[cc]; }
  float inv = -1.f/sum;
  float kv[36];
  if (half == 0){
    #pragma unroll
    for (int j = 0; j < 36; ++j) kv[j] = sv[j]*inv;
  } else {
    #pragma unroll
    for (int j = 0; j < 36; ++j) kv[j] = sv[36 + j]*inv;
  }
  #pragma unroll
  for (int c8 = 0; c8 < 4; ++c8) kv[c8*9 + 4] += 1.f;   // kern = delta - softmax

  // ---- 9 taps from LDS window, o[32] accum ----
  float o[32];
  #pragma unroll
  for (int cc = 0; cc < 32; ++cc) o[cc] = 0.f;
  #pragma unroll
  for (int i = 0; i < 3; ++i){
    #pragma unroll
    for (int j = 0; j < 3; ++j){
      int wcol = c + j, wrow = r + i;
      #pragma unroll
      for (int c8 = 0; c8 < 4; ++c8){
        int L = (wrow*8 + half*4 + c8)*66 + wcol;
        uint4 v = *(const uint4*)(smem + ((size_t)L << 4));
        const u16* e = (const u16*)&v;
        float k = kv[c8*9 + i*3 + j];
        #pragma unroll
        for (int jj = 0; jj < 8; ++jj) o[c8*8 + jj] = fmaf(k, b2f(e[jj]), o[c8*8 + jj]);
      }
    }
  }
  __syncthreads();   // window dead; alias obuf/ps

  u16* obuf = (u16*)smem;               // 128*66 u16 = 16,896 B
  float* ps = (float*)(smem + 20480);   // [8][32][2] = 2 KB
  #pragma unroll
  for (int c8 = 0; c8 < 4; ++c8){
    u16 ob[8];
    #pragma unroll
    for (int jj = 0; jj < 8; ++jj) ob[jj] = f2b(o[c8*8 + jj]);
    *(uint4*)(obuf + p*66 + (half*4 + c8)*8) = *(uint4*)ob;
  }
  __syncthreads();

  // HIN partial stats (channels 0..31), transpose read
  {
    int cch = t & 31, seg = t >> 5;    // 8 segs x 16 px
    float s = 0.f, q = 0.f;
    #pragma unroll
    for (int rr = 0; rr < 16; ++rr){
      float v = b2f(obuf[(seg*16 + rr)*66 + cch]);
      s += v; q += v*v;
    }
    ps[(seg*32 + cch)*2 + 0] = s; ps[(seg*32 + cch)*2 + 1] = q;
  }
  // coalesced y2pad write
  for (int idx = t; idx < 1024; idx += 256){
    int pp = idx >> 3, j = idx & 7;
    int rr = pp >> 6, cc = pp & 63;
    uint4 v = *(const uint4*)(obuf + pp*66 + j*8);
    *(uint4*)(y2pad + ((size_t)(n*PD + h0 + 1 + rr)*PD + (w0 + 1 + cc))*CIN + j*8) = v;
  }
  __syncthreads();
  if (t < 64){
    int cc = t >> 1, which = t & 1;
    float v = 0.f;
    #pragma unroll
    for (int seg = 0; seg < 8; ++seg) v += ps[(seg*32 + cc)*2 + which];
    atomicAdd(which ? &hinsumsq[n*32 + cc] : &hinsum[n*32 + cc], v);
  }
}

__global__ void hinfinal_kernel(const float* __restrict__ hinsum, const float* __restrict__ hinsumsq,
                                float* __restrict__ hmu, float* __restrict__ hrs){
  int i = threadIdx.x;
  if (i < 128){
    const float M = 65536.f;
    float mu  = hinsum[i] / M;
    float var = hinsumsq[i] / M - mu*mu;
    hmu[i] = mu;
    hrs[i] = rsqrtf(var + EPSV);
  }
}

// ---------- launch ----------
extern "C" void kernel_launch(void* const* d_in, const int* in_sizes, int n_in,
                              void* d_out, int out_size, void* d_ws, size_t ws_size,
                              hipStream_t stream){
  const float* x     = (const float*)d_in[0];
  const float* w1    = (const float*)d_in[1];
  const float* b1    = (const float*)d_in[2];
  const float* wf    = (const float*)d_in[3];
  const float* gamma = (const float*)d_in[4];
  const float* beta  = (const float*)d_in[5];
  const float* w2    = (const float*)d_in[6];
  const float* b2    = (const float*)d_in[7];
  const float* wr    = (const float*)d_in[8];
  const float* br    = (const float*)d_in[9];

  char* ws = (char*)d_ws;
  const size_t PADB = (size_t)NN*PD*PD*CIN*2;   // 34,080,768 bytes
  u16* xpad  = (u16*)(ws);
  u16* y1pad = (u16*)(ws + PADB);
  u16* y2pad = (u16*)(ws + 2*PADB);
  float* stats = (float*)(ws + 3*PADB);
  float* bnsum   = stats;        float* bnsumsq = stats + 80;
  float* bnscale = stats + 160;  float* bnshift = stats + 240;
  float* hinsum  = stats + 320;  float* hinsumsq= stats + 448;
  float* hmu     = stats + 576;  float* hrs     = stats + 704;
  u16* wB1 = (u16*)(ws + 3*PADB + 4096);
  u16* wBf = wB1 + 36864;
  u16* wB2 = wBf + 55296;
  u16* wBr = wB2 + 36864;

  u16* sig = (u16*)d_out;        // 37.7MB bf16 [n][hw][72], overwritten by conv2's f32 output later
  float* out = (float*)d_out;

  hipMemsetAsync(stats, 0, 4096, stream);
  prep_kernel<<<256, 256, 0, stream>>>(w1, wf, w2, wr, wB1, wBf, wB2, wBr);
  padx_kernel<<<NN*HH, 256, 0, stream>>>(x, xpad);
  conv_mfma<2,0><<<2048, 256, 0, stream>>>(xpad, wB1, b1, y1pad, nullptr, nullptr, nullptr, nullptr, nullptr, nullptr, nullptr, nullptr);
  reflect_kernel<<<(4*1028*8 + 255)/256, 256, 0, stream>>>(y1pad);
  conv_mfma<3,1><<<2048, 384, 0, stream>>>(y1pad, wBf, nullptr, sig, nullptr, nullptr, nullptr, nullptr, bnsum, bnsumsq, nullptr, nullptr);
  bnfinal_kernel<<<1, 80, 0, stream>>>(bnsum, bnsumsq, gamma, beta, bnscale, bnshift);
  filter_kernel<<<2048, 256, 0, stream>>>(sig, y1pad, bnscale, bnshift, y2pad, hinsum, hinsumsq);
  hinfinal_kernel<<<1, 128, 0, stream>>>(hinsum, hinsumsq, hmu, hrs);
  conv_mfma<2,2><<<2048, 256, 0, stream>>>(y2pad, wB2, b2, nullptr, out, xpad, wBr, br, nullptr, nullptr, hmu, hrs);
}